// Round 6
// baseline (3248.413 us; speedup 1.0000x reference)
//
#include <hip/hip_runtime.h>
#include <hip/hip_bf16.h>
#include <math.h>

// Model dims
#define BATCH 2
#define SEQ   2048
#define BSQ   4096          // BATCH*SEQ
#define DIM   2304          // = 9*256
#define NH    8
#define NKVH  4
#define HDIM  256
#define FFDIM 9216
#define QKVN  4096          // (NH + 2*NKVH)*HDIM
#define QOFF  0
#define KOFF  2048          // NH*HDIM
#define VOFF  3072          // NH*HDIM + NKVH*HDIM
#define WIN_M1 1023         // WIN-1
#define QSCALE 0.0625f      // 256^-0.5
#define SOFTCAP 50.0f

typedef __attribute__((ext_vector_type(8))) short short8;
typedef __attribute__((ext_vector_type(4))) float f32x4;
typedef __hip_bfloat16 bf16;

__device__ __forceinline__ void gload16(void* lds, const void* g) {
  // async global->LDS, 16B per lane; LDS dest must be wave-uniform base (+lane*16 in HW)
  __builtin_amdgcn_global_load_lds((const __attribute__((address_space(1))) void*)g,
                                   (__attribute__((address_space(3))) void*)lds, 16, 0, 0);
}

__device__ __forceinline__ float blockReduceSum256(float v, float* red) {
  int tid = threadIdx.x;
  red[tid] = v; __syncthreads();
  #pragma unroll
  for (int s = 128; s > 0; s >>= 1) {
    if (tid < s) red[tid] += red[tid + s];
    __syncthreads();
  }
  float r = red[0];
  __syncthreads();
  return r;
}

// ---------------- embedding ----------------
__global__ void k_embed(float* __restrict__ h, const int* __restrict__ tokens,
                        const float* __restrict__ embed) {
  int row = blockIdx.x;
  int tok = tokens[row];
  const float* src = embed + (size_t)tok * DIM;
  float* dst = h + (size_t)row * DIM;
  for (int d = threadIdx.x; d < DIM; d += 256) dst[d] = src[d] * 48.0f; // sqrt(2304)=48
}

// ---------------- rmsnorm: MODE 0 = write bf16, 2 = write fp32 ----------------
template<int MODE>
__global__ void k_rmsnorm(void* __restrict__ outv, const float* __restrict__ in,
                          const float* __restrict__ w) {
  __shared__ float red[256];
  int row = blockIdx.x, tid = threadIdx.x;
  const float* p = in + (size_t)row * DIM;
  float ss = 0.f;
  for (int d = tid; d < DIM; d += 256) { float v = p[d]; ss += v * v; }
  ss = blockReduceSum256(ss, red);
  float inv = 1.0f / sqrtf(ss / (float)DIM + 1e-6f);
  for (int d = tid; d < DIM; d += 256) {
    float v = p[d] * inv * (1.0f + w[d]);
    if (MODE == 0) ((bf16*)outv)[(size_t)row * DIM + d] = __float2bfloat16(v);
    else ((float*)outv)[(size_t)row * DIM + d] = v;
  }
}

// ------- fused: h += rmsnorm(in, w1); out = rmsnorm(h, w2)  (row in registers) ------
// Safe when outv aliases in: all reads of `in` complete (into pv[]) before any outv write.
template<int OUT_BF16>
__global__ __launch_bounds__(256)
void k_addnorm2(float* __restrict__ h, const float* __restrict__ in,
                const float* __restrict__ w1, const float* __restrict__ w2,
                void* __restrict__ outv) {
  __shared__ float red[256];
  int row = blockIdx.x, tid = threadIdx.x;
  const float* p = in + (size_t)row * DIM;
  float* hp = h + (size_t)row * DIM;
  float pv[9], hv[9];
  float ss = 0.f;
  #pragma unroll
  for (int i = 0; i < 9; i++) {
    int d = tid + i * 256;
    pv[i] = p[d]; hv[i] = hp[d];
    ss += pv[i] * pv[i];
  }
  ss = blockReduceSum256(ss, red);
  float inv = 1.0f / sqrtf(ss / (float)DIM + 1e-6f);
  float ss2 = 0.f;
  #pragma unroll
  for (int i = 0; i < 9; i++) {
    int d = tid + i * 256;
    hv[i] += pv[i] * inv * (1.0f + w1[d]);
    ss2 += hv[i] * hv[i];
    hp[d] = hv[i];
  }
  ss2 = blockReduceSum256(ss2, red);
  float inv2 = 1.0f / sqrtf(ss2 / (float)DIM + 1e-6f);
  #pragma unroll
  for (int i = 0; i < 9; i++) {
    int d = tid + i * 256;
    float v = hv[i] * inv2 * (1.0f + w2[d]);
    if (OUT_BF16) ((bf16*)outv)[(size_t)row * DIM + d] = __float2bfloat16(v);
    else          ((float*)outv)[(size_t)row * DIM + d] = v;
  }
}

// ---------------- RoPE table (once per call) ----------------
__global__ void k_rope_tab(float* __restrict__ ct, float* __restrict__ st) {
  int idx = blockIdx.x * 256 + threadIdx.x;   // pos*128 + d
  int d = idx & 127, pos = idx >> 7;
  double inv = pow(10000.0, -(double)d / 128.0);
  double ang = (double)pos * inv;
  ct[idx] = (float)cos(ang);
  st[idx] = (float)sin(ang);
}

// ---- rope + bf16 pack: qkv fp32 -> Qb [b][h][s][256] (scaled), Kb [b][kvh][s][256] ----
__global__ __launch_bounds__(256)
void k_ropepack(bf16* __restrict__ Qb, bf16* __restrict__ Kb,
                const float* __restrict__ qkv, const float* __restrict__ ct,
                const float* __restrict__ st) {
  int pos = blockIdx.x, b = blockIdx.y, t = threadIdx.x;
  const float* row = qkv + (size_t)(b * SEQ + pos) * QKVN;
  int hd = t >> 5, d1 = (t & 31) * 4;
  const float* q = row + QOFF + hd * HDIM;
  bf16* qo = Qb + (((size_t)b * NH + hd) * SEQ + pos) * HDIM;
  #pragma unroll
  for (int i = 0; i < 4; i++) {
    float c = ct[pos * 128 + d1 + i], s = st[pos * 128 + d1 + i];
    float x1 = q[d1 + i], x2 = q[d1 + i + 128];
    qo[d1 + i]       = __float2bfloat16((x1 * c - x2 * s) * QSCALE);
    qo[d1 + i + 128] = __float2bfloat16((x1 * s + x2 * c) * QSCALE);
  }
  if (t < 128) {
    int kh = t >> 5; d1 = (t & 31) * 4;
    const float* k = row + KOFF + kh * HDIM;
    bf16* ko = Kb + (((size_t)b * NKVH + kh) * SEQ + pos) * HDIM;
    #pragma unroll
    for (int i = 0; i < 4; i++) {
      float c = ct[pos * 128 + d1 + i], s = st[pos * 128 + d1 + i];
      float x1 = k[d1 + i], x2 = k[d1 + i + 128];
      ko[d1 + i]       = __float2bfloat16(x1 * c - x2 * s);
      ko[d1 + i + 128] = __float2bfloat16(x1 * s + x2 * c);
    }
  }
}

// ---- V transpose + bf16: qkv fp32 [s][d] (strided) -> Vt [b][kvh][d=256][s=2048] ----
__global__ __launch_bounds__(256)
void k_vT(bf16* __restrict__ Vt, const float* __restrict__ qkv) {
  __shared__ float tbuf[32][33];
  int b = blockIdx.z >> 2, kvh = blockIdx.z & 3;
  int pos0 = blockIdx.x * 32, d0 = blockIdx.y * 32;
  int tx = threadIdx.x & 31, ty = threadIdx.x >> 5;
  const float* src = qkv + VOFF + kvh * HDIM;
  #pragma unroll
  for (int r = 0; r < 32; r += 8)
    tbuf[ty + r][tx] = src[(size_t)(b * SEQ + pos0 + ty + r) * QKVN + d0 + tx];
  __syncthreads();
  bf16* dst = Vt + ((size_t)b * NKVH + kvh) * HDIM * SEQ;
  #pragma unroll
  for (int r = 0; r < 32; r += 8)
    dst[(size_t)(d0 + ty + r) * SEQ + pos0 + tx] = __float2bfloat16(tbuf[tx][ty + r]);
}

// ---------------- MFMA flash attention ----------------
// Block: 256 thr (4 waves), handles (b, h, 64-query tile). Wave w owns q rows w*16..+16.
// LDS: Qs[64][256] Ks[32][256] (512B rows, chunk^=(r&7) swizzle), Vs[256][32] (64B rows,
// chunk^=(r&3)), Ps[64][32] linear. Swizzle is both-sides: linear gload dest + inverse-
// swizzled global src + swizzled ds_read (involution).
__global__ __launch_bounds__(256)
void k_attn3(bf16* __restrict__ ctx, const bf16* __restrict__ Qb,
             const bf16* __restrict__ Kb, const bf16* __restrict__ Vt, int sliding) {
  __shared__ bf16 Qs[64 * 256];
  __shared__ bf16 Ks[32 * 256];
  __shared__ bf16 Vs[256 * 32];
  __shared__ bf16 Ps[64 * 32];
  int tid = threadIdx.x, w = tid >> 6, l = tid & 63;
  int qt = blockIdx.x, hh = blockIdx.y, b = blockIdx.z;
  int kvh = hh >> 1, q0 = qt * 64;
  int l15 = l & 15, l4 = l >> 4;

  // stage Q once: 64 rows x 512B, swizzled placement via global-src pre-swizzle
  const char* Qg = (const char*)(Qb + (((size_t)b * NH + hh) * SEQ + q0) * HDIM);
  #pragma unroll
  for (int i = 0; i < 8; i++) {
    int base16 = i * 256 + w * 64;          // wave-uniform 16B-chunk index
    int p16 = base16 + l;
    int r = p16 >> 5, cl = p16 & 31, cg = cl ^ (r & 7);
    gload16((char*)Qs + (size_t)base16 * 16, Qg + (size_t)r * 512 + cg * 16);
  }

  const char* Kg = (const char*)(Kb + ((size_t)b * NKVH + kvh) * SEQ * HDIM);
  const char* Vg = (const char*)(Vt + ((size_t)b * NKVH + kvh) * HDIM * SEQ);

  f32x4 o[16];
  #pragma unroll
  for (int n = 0; n < 16; n++) o[n] = (f32x4){0.f, 0.f, 0.f, 0.f};
  float mrow[4] = {-3.0e38f, -3.0e38f, -3.0e38f, -3.0e38f};
  float lrow[4] = {0.f, 0.f, 0.f, 0.f};

  int t_lo = sliding ? (max(0, q0 - WIN_M1) & ~31) : 0;
  for (int kt = t_lo; kt < q0 + 64; kt += 32) {
    __syncthreads();                        // prev tile's PV readers done
    // stage K tile: 32 rows x 512B
    #pragma unroll
    for (int i = 0; i < 4; i++) {
      int base16 = i * 256 + w * 64;
      int p16 = base16 + l;
      int r = p16 >> 5, cl = p16 & 31, cg = cl ^ (r & 7);
      gload16((char*)Ks + (size_t)base16 * 16, Kg + (size_t)(kt + r) * 512 + cg * 16);
    }
    // stage V^T tile: 256 rows x 64B
    #pragma unroll
    for (int i = 0; i < 4; i++) {
      int base16 = i * 256 + w * 64;
      int p16 = base16 + l;
      int r = p16 >> 2, cl = p16 & 3, cg = cl ^ (r & 3);
      gload16((char*)Vs + (size_t)base16 * 16, Vg + (size_t)r * (SEQ * 2) + kt * 2 + cg * 16);
    }
    __syncthreads();                        // staging visible (vmcnt drained by barrier)

    // S = Q K^T : per wave 16q x 32k, K-dim 256 in 8 chunks
    f32x4 acc2[2] = {(f32x4){0,0,0,0}, (f32x4){0,0,0,0}};
    int ra = w * 16 + l15;
    #pragma unroll
    for (int c = 0; c < 8; c++) {
      int nom = c * 4 + l4;
      short8 a = *(const short8*)((const char*)Qs + (size_t)ra * 512 + ((nom ^ (ra & 7)) * 16));
      #pragma unroll
      for (int n = 0; n < 2; n++) {
        int rb = n * 16 + l15;
        short8 bf = *(const short8*)((const char*)Ks + (size_t)rb * 512 + ((nom ^ (rb & 7)) * 16));
        acc2[n] = __builtin_amdgcn_mfma_f32_16x16x32_bf16(a, bf, acc2[n], 0, 0, 0);
      }
    }

    // softcap + mask + online softmax (per q-row j; row spread over 16 lanes x 2 n-tiles)
    float sv[2][4], tmax[4];
    #pragma unroll
    for (int j = 0; j < 4; j++) tmax[j] = -3.0e38f;
    #pragma unroll
    for (int n = 0; n < 2; n++) {
      int key = kt + n * 16 + l15;
      #pragma unroll
      for (int j = 0; j < 4; j++) {
        int qrow = q0 + w * 16 + l4 * 4 + j;
        bool valid = (key <= qrow) && (!sliding || key >= qrow - WIN_M1);
        float s = tanhf(acc2[n][j] * (1.0f / SOFTCAP)) * SOFTCAP;
        sv[n][j] = valid ? s : -3.0e38f;
        tmax[j] = fmaxf(tmax[j], sv[n][j]);
      }
    }
    #pragma unroll
    for (int j = 0; j < 4; j++) {
      float t = tmax[j];
      t = fmaxf(t, __shfl_xor(t, 1)); t = fmaxf(t, __shfl_xor(t, 2));
      t = fmaxf(t, __shfl_xor(t, 4)); t = fmaxf(t, __shfl_xor(t, 8));
      tmax[j] = t;
    }
    float factor[4], psum[4];
    #pragma unroll
    for (int j = 0; j < 4; j++) {
      float mnew = fmaxf(mrow[j], tmax[j]);
      factor[j] = expf(mrow[j] - mnew);     // (-inf)-(-inf) -> exp(0)=1: harmless, o=l=0
      mrow[j] = mnew;
      lrow[j] *= factor[j];
      psum[j] = 0.f;
    }
    #pragma unroll
    for (int n = 0; n < 2; n++)
      #pragma unroll
      for (int j = 0; j < 4; j++) {
        float p = (sv[n][j] > -1.0e38f) ? expf(sv[n][j] - mrow[j]) : 0.f; // explicit gate
        psum[j] += p;
        Ps[(w * 16 + l4 * 4 + j) * 32 + n * 16 + l15] = __float2bfloat16(p);
      }
    #pragma unroll
    for (int j = 0; j < 4; j++) {
      float t = psum[j];
      t += __shfl_xor(t, 1); t += __shfl_xor(t, 2);
      t += __shfl_xor(t, 4); t += __shfl_xor(t, 8);
      lrow[j] += t;
    }
    #pragma unroll
    for (int n = 0; n < 16; n++)
      #pragma unroll
      for (int j = 0; j < 4; j++) o[n][j] *= factor[j];
    __syncthreads();                        // Ps writes visible (wave-private rows, but safe)

    // O += P V : per wave 16q x 256d, K-dim 32 (one MFMA chunk)
    short8 pa = *(const short8*)((const bf16*)Ps + (size_t)(w * 16 + l15) * 32 + l4 * 8);
    #pragma unroll
    for (int n = 0; n < 16; n++) {
      int r = n * 16 + l15;
      short8 vb = *(const short8*)((const char*)Vs + (size_t)r * 64 + ((l4 ^ (r & 3)) * 16));
      o[n] = __builtin_amdgcn_mfma_f32_16x16x32_bf16(pa, vb, o[n], 0, 0, 0);
    }
  }

  float rinv[4];
  #pragma unroll
  for (int j = 0; j < 4; j++) rinv[j] = 1.0f / lrow[j];
  #pragma unroll
  for (int n = 0; n < 16; n++)
    #pragma unroll
    for (int j = 0; j < 4; j++) {
      int qrow = q0 + w * 16 + l4 * 4 + j;
      ctx[(size_t)(b * SEQ + qrow) * 2048 + hh * HDIM + n * 16 + l15] =
          __float2bfloat16(o[n][j] * rinv[j]);
    }
}

// ---------------- weight convert + transpose: fp32 [K][N] -> bf16 [N][K] ----------
__global__ __launch_bounds__(256)
void k_convT(bf16* __restrict__ out, const float* __restrict__ in, int K, int N) {
  __shared__ float t[32][33];
  int kb = blockIdx.y * 32, nb = blockIdx.x * 32;
  int tx = threadIdx.x & 31, ty = threadIdx.x >> 5;
  #pragma unroll
  for (int r = 0; r < 32; r += 8)
    t[ty + r][tx] = in[(size_t)(kb + ty + r) * N + nb + tx];
  __syncthreads();
  #pragma unroll
  for (int r = 0; r < 32; r += 8)
    out[(size_t)(nb + ty + r) * K + kb + tx] = __float2bfloat16(t[tx][ty + r]);
}

// ---------------- bf16 MFMA GEMM (m97 structure): C(MxN) = A(MxK) @ Bt(NxK)^T -----
__device__ __forceinline__ float gelu_tanh(float v) {
  return 0.5f * v * (1.0f + tanhf(0.7978845608028654f * (v + 0.044715f * v * v * v)));
}

template<int EPI>
__global__ __launch_bounds__(256)
void k_gemm_bf16(void* __restrict__ Cout, const bf16* __restrict__ A,
                 const bf16* __restrict__ Bt, const bf16* __restrict__ U,
                 int M, int N, int K) {
  __shared__ bf16 As[128 * 32];
  __shared__ bf16 Bs[128 * 32];
  int tid = threadIdx.x;
  int w = tid >> 6, l = tid & 63;
  int bm = blockIdx.y, bn = blockIdx.x;
  int wr = w >> 1, wc = w & 1;
  f32x4 acc[4][4] = {};
  const bf16* Abase = A + (size_t)(bm * 128) * K;
  const bf16* Bbase = Bt + (size_t)(bn * 128) * K;
  int lrow = l >> 2;
  int lcol = (l & 3) * 8;
  int lr = l & 15, lk = (l >> 4) * 8;

  for (int k0 = 0; k0 < K; k0 += 32) {
    #pragma unroll
    for (int r = 0; r < 2; r++) {
      int rbase = r * 64 + w * 16;
      gload16(&As[rbase * 32], Abase + (size_t)(rbase + lrow) * K + k0 + lcol);
      gload16(&Bs[rbase * 32], Bbase + (size_t)(rbase + lrow) * K + k0 + lcol);
    }
    __syncthreads();
    short8 a[4], b[4];
    #pragma unroll
    for (int m = 0; m < 4; m++)
      a[m] = *(const short8*)&As[(wr * 64 + m * 16 + lr) * 32 + lk];
    #pragma unroll
    for (int n = 0; n < 4; n++)
      b[n] = *(const short8*)&Bs[(wc * 64 + n * 16 + lr) * 32 + lk];
    #pragma unroll
    for (int m = 0; m < 4; m++)
      #pragma unroll
      for (int n = 0; n < 4; n++)
        acc[m][n] = __builtin_amdgcn_mfma_f32_16x16x32_bf16(a[m], b[n], acc[m][n], 0, 0, 0);
    __syncthreads();
  }

  int cr = (l >> 4) * 4, cc = l & 15;
  int grow = bm * 128 + wr * 64, gcol = bn * 128 + wc * 64;
  #pragma unroll
  for (int m = 0; m < 4; m++)
    #pragma unroll
    for (int n = 0; n < 4; n++)
      #pragma unroll
      for (int j = 0; j < 4; j++) {
        size_t idx = (size_t)(grow + m * 16 + cr + j) * N + gcol + n * 16 + cc;
        float v = acc[m][n][j];
        if (EPI == 0)      ((float*)Cout)[idx] = v;
        else if (EPI == 1) ((bf16*)Cout)[idx] =
            __float2bfloat16(gelu_tanh(v) * __bfloat162float(U[idx]));
        else               ((bf16*)Cout)[idx] = __float2bfloat16(v);
      }
}

extern "C" void kernel_launch(void* const* d_in, const int* in_sizes, int n_in,
                              void* d_out, int out_size, void* d_ws, size_t ws_size,
                              hipStream_t stream) {
  const int*   tokens       = (const int*)d_in[0];
  const float* embed        = (const float*)d_in[1];
  const float* qkv_w        = (const float*)d_in[2];
  const float* o_w          = (const float*)d_in[3];
  const float* gate_w       = (const float*)d_in[4];
  const float* up_w         = (const float*)d_in[5];
  const float* down_w       = (const float*)d_in[6];
  const float* ln_in        = (const float*)d_in[7];
  const float* ln_post_attn = (const float*)d_in[8];
  const float* ln_pre_ffw   = (const float*)d_in[9];
  const float* ln_post_ffw  = (const float*)d_in[10];
  const float* ln_final     = (const float*)d_in[11];
  float* out = (float*)d_out;

  // ---- workspace layout (aligned 256B), ~210MB total ----
  size_t off = 0;
  char* base = (char*)d_ws;
  auto alloc = [&](size_t bytes) { void* p = base + off; off += (bytes + 255) & ~255ULL; return p; };
  bf16* wT    = (bf16*)alloc((size_t)FFDIM * DIM * 2);   // rotating weight buf (max 9216x2304)
  float* h    = (float*)alloc((size_t)BSQ * DIM * 4);
  bf16*  x    = (bf16*) alloc((size_t)BSQ * DIM * 2);
  float* ctab = (float*)alloc((size_t)SEQ * 128 * 4);
  float* stab = (float*)alloc((size_t)SEQ * 128 * 4);
  bf16* Qb    = (bf16*)alloc((size_t)BATCH * NH * SEQ * HDIM * 2);    // 16.8MB
  bf16* Kb    = (bf16*)alloc((size_t)BATCH * NKVH * SEQ * HDIM * 2);  // 8.4MB
  bf16* Vt    = (bf16*)alloc((size_t)BATCH * NKVH * HDIM * SEQ * 2);  // 8.4MB
  // union region: qkv fp32 (dead after pack/vT; ctx aliases it) vs ff bf16
  size_t qkvB = (size_t)BSQ * QKVN * 4;                  // 67.1MB
  size_t ffB  = (size_t)BSQ * FFDIM * 2;                 // 75.5MB
  char* ureg  = (char*)alloc(qkvB > ffB ? qkvB : ffB);
  float* qkv  = (float*)ureg;
  bf16*  ctx  = (bf16*)ureg;    // written after qkv is dead (post pack/vT)
  bf16*  ff   = (bf16*)ureg;    // written after ctx is consumed (post o-proj)
  float* proj = out;            // d_out doubles as proj scratch (exactly BSQ*DIM fp32)

  k_rope_tab<<<SEQ * 128 / 256, 256, 0, stream>>>(ctab, stab);
  k_embed<<<BSQ, 256, 0, stream>>>(h, tokens, embed);
  k_rmsnorm<0><<<BSQ, 256, 0, stream>>>(x, h, ln_in + 0 * DIM);

  for (int l = 0; l < 2; l++) {
    // ---- attention block ----
    k_convT<<<dim3(QKVN / 32, DIM / 32), 256, 0, stream>>>(
        wT, qkv_w + (size_t)l * DIM * QKVN, DIM, QKVN);
    k_gemm_bf16<0><<<dim3(QKVN / 128, BSQ / 128), 256, 0, stream>>>(
        qkv, x, wT, nullptr, BSQ, QKVN, DIM);
    k_ropepack<<<dim3(SEQ, BATCH), 256, 0, stream>>>(Qb, Kb, qkv, ctab, stab);
    k_vT<<<dim3(SEQ / 32, HDIM / 32, BATCH * NKVH), 256, 0, stream>>>(Vt, qkv);
    k_attn3<<<dim3(SEQ / 64, NH, BATCH), 256, 0, stream>>>(
        ctx, Qb, Kb, Vt, (l % 2 == 0) ? 1 : 0);
    k_convT<<<dim3(DIM / 32, 2048 / 32), 256, 0, stream>>>(
        wT, o_w + (size_t)l * 2048 * DIM, 2048, DIM);
    k_gemm_bf16<0><<<dim3(DIM / 128, BSQ / 128), 256, 0, stream>>>(
        proj, ctx, wT, nullptr, BSQ, DIM, 2048);
    k_addnorm2<1><<<BSQ, 256, 0, stream>>>(h, proj, ln_post_attn + l * DIM,
                                           ln_pre_ffw + l * DIM, x);

    // ---- MLP block ----
    k_convT<<<dim3(FFDIM / 32, DIM / 32), 256, 0, stream>>>(
        wT, up_w + (size_t)l * DIM * FFDIM, DIM, FFDIM);
    k_gemm_bf16<2><<<dim3(FFDIM / 128, BSQ / 128), 256, 0, stream>>>(
        ff, x, wT, nullptr, BSQ, FFDIM, DIM);                     // up -> ff
    k_convT<<<dim3(FFDIM / 32, DIM / 32), 256, 0, stream>>>(
        wT, gate_w + (size_t)l * DIM * FFDIM, DIM, FFDIM);
    k_gemm_bf16<1><<<dim3(FFDIM / 128, BSQ / 128), 256, 0, stream>>>(
        ff, x, wT, ff, BSQ, FFDIM, DIM);                          // gelu(gate)*ff
    k_convT<<<dim3(DIM / 32, FFDIM / 32), 256, 0, stream>>>(
        wT, down_w + (size_t)l * FFDIM * DIM, FFDIM, DIM);
    k_gemm_bf16<0><<<dim3(DIM / 128, BSQ / 128), 256, 0, stream>>>(
        proj, ff, wT, nullptr, BSQ, DIM, FFDIM);                  // down
    if (l == 0) {
      k_addnorm2<1><<<BSQ, 256, 0, stream>>>(h, proj, ln_post_ffw + l * DIM,
                                             ln_in + (l + 1) * DIM, x);
    } else {
      k_addnorm2<0><<<BSQ, 256, 0, stream>>>(h, proj, ln_post_ffw + l * DIM,
                                             ln_final, out);
    }
  }
}